// Round 1
// baseline (175.431 us; speedup 1.0000x reference)
//
#include <hip/hip_runtime.h>
#include <hip/hip_bf16.h>
#include <stdint.h>

typedef unsigned short ushort_t;
typedef __attribute__((ext_vector_type(8))) short short8;
typedef __attribute__((ext_vector_type(4))) float f32x4;

#define DIM 64
#define NGROUP 280          // padded groups of 8 pairs (i fixed, j0 8-aligned)
#define NSTEP 70            // NGROUP/4 K-steps of K=32
#define BM 256              // rows per block
#define XS_STRIDE 68        // padded LDS row stride (floats): 272B = 16B-aligned, %32 banks = 4

// gid -> (i, j0): groups enumerated as {for i in 0..63: for j0 in 8*floor((i+1)/8)..56 step 8}
__device__ inline void gid_to_ij(int gid, int& i_out, int& j0_out) {
    int cum = 0;
    i_out = 0; j0_out = 0;
    #pragma unroll
    for (int ii = 0; ii < 64; ++ii) {
        int jstart = ((ii + 1) >> 3) << 3;
        int ng = (64 - jstart) >> 3;
        if (gid >= cum && gid < cum + ng) {
            i_out = ii;
            j0_out = jstart + (gid - cum) * 8;
        }
        cum += ng;
    }
}

// Prep: split w1 into bf16 hi/lo, pre-swizzled into MFMA B-fragment order.
// Layout: elem offset = ((s*4 + t)*64 + lane)*8 + e  for step s, n-tile t, lane, k-elem e.
__global__ void wpack_kernel(const float* __restrict__ w1,
                             ushort_t* __restrict__ w_hi,
                             ushort_t* __restrict__ w_lo,
                             uint32_t* __restrict__ idx_tab) {
    int id = blockIdx.x * 256 + threadIdx.x;
    if (id >= NGROUP * 8 * 64) return;
    int n   = id & 63;          // output column 0..63
    int e   = (id >> 6) & 7;    // k-elem within group
    int gid = id >> 9;          // group 0..279
    int i, j0;
    gid_to_ij(gid, i, j0);
    int j = j0 + e;
    float w = 0.0f;
    if (j > i) {  // j < 64 guaranteed by construction
        int p = i * DIM - (i * (i + 1)) / 2 + (j - i - 1);
        w = w1[p * DIM + n];
    }
    __hip_bfloat16 hb = __float2bfloat16(w);
    float hf = __bfloat162float(hb);
    float lo = w - hf;
    __hip_bfloat16 lb = __float2bfloat16(lo);

    int s = gid >> 2, g = gid & 3;
    int t = n >> 4, c = n & 15;
    int lane = g * 16 + c;
    size_t off = ((size_t)(s * 4 + t) * 64 + (size_t)lane) * 8 + (size_t)e;
    w_hi[off] = *reinterpret_cast<ushort_t*>(&hb);
    w_lo[off] = *reinterpret_cast<ushort_t*>(&lb);
    if (e == 0 && n == 0) idx_tab[gid] = (uint32_t)i | ((uint32_t)j0 << 8);
}

__global__ __launch_bounds__(256, 2)
void prodres_kernel(const float* __restrict__ x,
                    const ushort_t* __restrict__ w_hi,
                    const ushort_t* __restrict__ w_lo,
                    const uint32_t* __restrict__ idx_tab,
                    float* __restrict__ out) {
    __shared__ float xs[BM * XS_STRIDE];
    __shared__ uint32_t idx_s[NGROUP];

    const int t    = threadIdx.x;
    const int lane = t & 63;
    const int wave = t >> 6;
    const long brow = (long)blockIdx.x * BM;

    // stage x tile [BM][64] -> xs (stride 68), coalesced float4 loads
    #pragma unroll
    for (int it = 0; it < 16; ++it) {
        int row = it * 16 + (t >> 4);
        int c   = (t & 15) * 4;
        float4 v = *reinterpret_cast<const float4*>(x + (brow + row) * DIM + c);
        float* dst = &xs[row * XS_STRIDE + c];
        dst[0] = v.x; dst[1] = v.y; dst[2] = v.z; dst[3] = v.w;
    }
    for (int ii = t; ii < NGROUP; ii += 256) idx_s[ii] = idx_tab[ii];
    __syncthreads();

    const int lrow = lane & 15;   // A row / C col within 16-tile
    const int g    = lane >> 4;   // k-group (owns k = g*8 + e)

    f32x4 acc[4][4];
    #pragma unroll
    for (int m = 0; m < 4; ++m)
        #pragma unroll
        for (int n = 0; n < 4; ++n) {
            f32x4 z = {0.f, 0.f, 0.f, 0.f};
            acc[m][n] = z;
        }

    for (int s = 0; s < NSTEP; ++s) {
        // ---- B fragments: direct coalesced global loads (L1/L2-hot, pre-swizzled) ----
        short8 bh[4], bl[4];
        #pragma unroll
        for (int n = 0; n < 4; ++n) {
            size_t off = ((size_t)(s * 4 + n) * 64 + (size_t)lane) * 8;
            bh[n] = *reinterpret_cast<const short8*>(w_hi + off);
            bl[n] = *reinterpret_cast<const short8*>(w_lo + off);
        }

        // ---- A fragments: on-the-fly pairwise products, split into bf16 hi/lo ----
        uint32_t ij = idx_s[s * 4 + g];
        int i  = (int)(ij & 0xffu);
        int j0 = (int)((ij >> 8) & 0xffu);

        short8 ah[4], al[4];
        #pragma unroll
        for (int m = 0; m < 4; ++m) {
            int row = wave * 64 + m * 16 + lrow;
            const float* xr = &xs[row * XS_STRIDE];
            float xi = xr[i];
            float4 xj0 = *reinterpret_cast<const float4*>(xr + j0);
            float4 xj1 = *reinterpret_cast<const float4*>(xr + j0 + 4);
            float p[8];
            p[0] = xi * xj0.x; p[1] = xi * xj0.y; p[2] = xi * xj0.z; p[3] = xi * xj0.w;
            p[4] = xi * xj1.x; p[5] = xi * xj1.y; p[6] = xi * xj1.z; p[7] = xi * xj1.w;
            #pragma unroll
            for (int e = 0; e < 8; ++e) {
                uint32_t ub = __builtin_bit_cast(uint32_t, p[e]);
                float hf = __builtin_bit_cast(float, ub & 0xFFFF0000u);
                float lo = p[e] - hf;                       // exact
                __hip_bfloat16 lb = __float2bfloat16(lo);   // RTN
                ah[m][e] = (short)(ub >> 16);
                al[m][e] = *reinterpret_cast<short*>(&lb);
            }
        }

        // ---- MFMAs: ah*wh + al*wh + ah*wl ----
        #pragma unroll
        for (int m = 0; m < 4; ++m)
            #pragma unroll
            for (int n = 0; n < 4; ++n) {
                acc[m][n] = __builtin_amdgcn_mfma_f32_16x16x32_bf16(ah[m], bh[n], acc[m][n], 0, 0, 0);
                acc[m][n] = __builtin_amdgcn_mfma_f32_16x16x32_bf16(al[m], bh[n], acc[m][n], 0, 0, 0);
                acc[m][n] = __builtin_amdgcn_mfma_f32_16x16x32_bf16(ah[m], bl[n], acc[m][n], 0, 0, 0);
            }
    }

    // ---- epilogue: C/D layout col=lane&15, row=(lane>>4)*4+reg; add residual x ----
    #pragma unroll
    for (int m = 0; m < 4; ++m)
        #pragma unroll
        for (int q = 0; q < 4; ++q) {
            int row = wave * 64 + m * 16 + g * 4 + q;
            #pragma unroll
            for (int n = 0; n < 4; ++n) {
                int col = n * 16 + lrow;
                out[(brow + row) * DIM + col] = acc[m][n][q] + xs[row * XS_STRIDE + col];
            }
        }
}

extern "C" void kernel_launch(void* const* d_in, const int* in_sizes, int n_in,
                              void* d_out, int out_size, void* d_ws, size_t ws_size,
                              hipStream_t stream) {
    const float* x  = (const float*)d_in[0];
    const float* w1 = (const float*)d_in[1];
    float* out = (float*)d_out;

    const size_t WELEMS = (size_t)NGROUP * 8 * 64;  // 143360 bf16 elems per buffer
    ushort_t* w_hi = (ushort_t*)d_ws;
    ushort_t* w_lo = w_hi + WELEMS;
    uint32_t* idx_tab = (uint32_t*)(w_lo + WELEMS);

    int b_total = in_sizes[0] / DIM;   // 131072

    wpack_kernel<<<(NGROUP * 8 * 64 + 255) / 256, 256, 0, stream>>>(w1, w_hi, w_lo, idx_tab);
    prodres_kernel<<<b_total / BM, 256, 0, stream>>>(x, w_hi, w_lo, idx_tab, out);
}

// Round 3
// 122.045 us; speedup vs baseline: 1.4374x; 1.4374x over previous
//
#include <hip/hip_runtime.h>
#include <hip/hip_bf16.h>
#include <stdint.h>

typedef unsigned short ushort_t;
typedef __attribute__((ext_vector_type(8))) _Float16 half8_t;
typedef __attribute__((ext_vector_type(4))) _Float16 half4_t;
typedef __attribute__((ext_vector_type(2))) _Float16 half2_t;
typedef __attribute__((ext_vector_type(4))) float f32x4;

#define DIM 64
#define NGROUP 280          // padded groups of 8 pairs (i fixed, j0 8-aligned)
#define NSTEP 70            // NGROUP/4 K-steps of K=32
#define BM 128              // rows per block (4 waves, 32 rows/wave)
#define XS_STRIDE 72        // LDS row stride in halves: 144B, 16B-aligned, stride%32banks=4

// gid -> (i, j0): groups enumerated as {for i in 0..63: for j0 in 8*floor((i+1)/8)..56 step 8}
__device__ inline void gid_to_ij(int gid, int& i_out, int& j0_out) {
    int cum = 0;
    i_out = 0; j0_out = 0;
    #pragma unroll
    for (int ii = 0; ii < 64; ++ii) {
        int jstart = ((ii + 1) >> 3) << 3;
        int ng = (64 - jstart) >> 3;
        if (gid >= cum && gid < cum + ng) {
            i_out = ii;
            j0_out = jstart + (gid - cum) * 8;
        }
        cum += ng;
    }
}

// Prep: w1 -> fp16, pre-swizzled into MFMA B-fragment order.
// Buffer layout: off = ((st)*64 + lane)*8 + e, st = s*4 + t (t = n-tile).
// Thread id == off directly -> fully coalesced 2B writes (pairs merge to dwords).
__global__ void wpack_kernel(const float* __restrict__ w1,
                             _Float16* __restrict__ w_h,
                             uint32_t* __restrict__ idx_tab) {
    int id = blockIdx.x * 256 + threadIdx.x;
    if (id >= NGROUP * 8 * 64) return;
    int e    = id & 7;
    int lane = (id >> 3) & 63;
    int st   = id >> 9;          // 0..279
    int s    = st >> 2;
    int t    = st & 3;           // n-tile
    int g    = lane >> 4;        // k-group
    int c    = lane & 15;        // column within n-tile
    int n    = t * 16 + c;
    int gid  = s * 4 + g;

    int i, j0;
    gid_to_ij(gid, i, j0);
    int j = j0 + e;
    float w = 0.0f;
    if (j > i) {
        int p = i * DIM - (i * (i + 1)) / 2 + (j - i - 1);
        w = w1[p * DIM + n];
    }
    w_h[id] = (_Float16)w;
    if (e == 0 && c == 0 && t == 0) idx_tab[gid] = (uint32_t)i | ((uint32_t)j0 << 8);
}

__global__ __launch_bounds__(256, 4)
void prodres_kernel(const float* __restrict__ x,
                    const _Float16* __restrict__ w_h,
                    const uint32_t* __restrict__ idx_tab,
                    float* __restrict__ out) {
    __shared__ _Float16 xs[BM * XS_STRIDE];
    __shared__ uint32_t idx_s[NGROUP];

    const int t    = threadIdx.x;
    const int lane = t & 63;
    const int wave = t >> 6;
    const long brow = (long)blockIdx.x * BM;

    // stage x tile [BM][64] -> xs as fp16 (stride 72), coalesced float4 loads
    #pragma unroll
    for (int it = 0; it < 8; ++it) {
        int row = it * 16 + (t >> 4);
        int c   = (t & 15) * 4;
        float4 v = *reinterpret_cast<const float4*>(x + (brow + row) * DIM + c);
        half4_t h;
        h[0] = (_Float16)v.x; h[1] = (_Float16)v.y;
        h[2] = (_Float16)v.z; h[3] = (_Float16)v.w;
        *reinterpret_cast<half4_t*>(&xs[row * XS_STRIDE + c]) = h;
    }
    for (int ii = t; ii < NGROUP; ii += 256) idx_s[ii] = idx_tab[ii];
    __syncthreads();

    const int lrow = lane & 15;   // A row / C col within 16-tile
    const int g    = lane >> 4;   // k-group (owns k = g*8 + e)

    f32x4 acc[2][4];
    #pragma unroll
    for (int m = 0; m < 2; ++m)
        #pragma unroll
        for (int n = 0; n < 4; ++n) {
            f32x4 z = {0.f, 0.f, 0.f, 0.f};
            acc[m][n] = z;
        }

    const half8_t* wp = reinterpret_cast<const half8_t*>(w_h);

    #pragma unroll 2
    for (int s = 0; s < NSTEP; ++s) {
        // ---- B fragments: coalesced 16B global loads (L1-hot, pre-swizzled) ----
        half8_t bh[4];
        #pragma unroll
        for (int n = 0; n < 4; ++n)
            bh[n] = wp[(s * 4 + n) * 64 + lane];

        // ---- A fragments: pairwise products via v_pk_mul_f16 ----
        uint32_t ij = idx_s[s * 4 + g];
        int i  = (int)(ij & 0xffu);
        int j0 = (int)((ij >> 8) & 0xffu);

        half8_t ah[2];
        #pragma unroll
        for (int m = 0; m < 2; ++m) {
            const _Float16* xr = &xs[(wave * 32 + m * 16 + lrow) * XS_STRIDE];
            _Float16 xi = xr[i];
            half2_t xi2 = {xi, xi};
            half8_t xj = *reinterpret_cast<const half8_t*>(xr + j0);  // 16B-aligned
            half2_t* ap = reinterpret_cast<half2_t*>(&ah[m]);
            const half2_t* jp = reinterpret_cast<const half2_t*>(&xj);
            #pragma unroll
            for (int e2 = 0; e2 < 4; ++e2) ap[e2] = xi2 * jp[e2];
        }

        // ---- single fp16 MFMA per tile ----
        #pragma unroll
        for (int m = 0; m < 2; ++m)
            #pragma unroll
            for (int n = 0; n < 4; ++n)
                acc[m][n] = __builtin_amdgcn_mfma_f32_16x16x32_f16(ah[m], bh[n], acc[m][n], 0, 0, 0);
    }

    // ---- epilogue: C/D layout col=lane&15, row=(lane>>4)*4+reg; residual from fp32 x ----
    #pragma unroll
    for (int m = 0; m < 2; ++m)
        #pragma unroll
        for (int q = 0; q < 4; ++q) {
            long row = brow + wave * 32 + m * 16 + g * 4 + q;
            #pragma unroll
            for (int n = 0; n < 4; ++n) {
                int col = n * 16 + lrow;
                out[row * DIM + col] = acc[m][n][q] + x[row * DIM + col];
            }
        }
}

extern "C" void kernel_launch(void* const* d_in, const int* in_sizes, int n_in,
                              void* d_out, int out_size, void* d_ws, size_t ws_size,
                              hipStream_t stream) {
    const float* x  = (const float*)d_in[0];
    const float* w1 = (const float*)d_in[1];
    float* out = (float*)d_out;

    const size_t WELEMS = (size_t)NGROUP * 8 * 64;  // 143360 fp16 elems
    _Float16* w_h = (_Float16*)d_ws;
    uint32_t* idx_tab = (uint32_t*)(w_h + WELEMS);

    int b_total = in_sizes[0] / DIM;   // 131072

    wpack_kernel<<<(NGROUP * 8 * 64 + 255) / 256, 256, 0, stream>>>(w1, w_h, idx_tab);
    prodres_kernel<<<b_total / BM, 256, 0, stream>>>(x, w_h, idx_tab, out);
}

// Round 4
// 113.174 us; speedup vs baseline: 1.5501x; 1.0784x over previous
//
#include <hip/hip_runtime.h>
#include <hip/hip_bf16.h>
#include <stdint.h>

typedef unsigned short ushort_t;
typedef __attribute__((ext_vector_type(8))) _Float16 half8_t;
typedef __attribute__((ext_vector_type(4))) _Float16 half4_t;
typedef __attribute__((ext_vector_type(2))) _Float16 half2_t;
typedef __attribute__((ext_vector_type(4))) float f32x4;

#define DIM 64
#define NGROUP 280          // padded groups of 8 pairs (i fixed, j0 8-aligned)
#define NSTEP 70            // NGROUP/4 K-steps of K=32
#define BM 256              // rows per block; 4 waves, each M=64 x N=64
#define XS_STRIDE 72        // LDS row stride in halves: 144B, 16B-aligned

// gid -> (i, j0): groups enumerated as {for i in 0..63: for j0 in 8*floor((i+1)/8)..56 step 8}
__device__ inline void gid_to_ij(int gid, int& i_out, int& j0_out) {
    int cum = 0;
    i_out = 0; j0_out = 0;
    #pragma unroll
    for (int ii = 0; ii < 64; ++ii) {
        int jstart = ((ii + 1) >> 3) << 3;
        int ng = (64 - jstart) >> 3;
        if (gid >= cum && gid < cum + ng) {
            i_out = ii;
            j0_out = jstart + (gid - cum) * 8;
        }
        cum += ng;
    }
}

// Prep: w1 -> fp16, pre-swizzled into MFMA B-fragment order.
// off = ((s*4 + t)*64 + lane)*8 + e; thread id == off -> coalesced writes.
__global__ void wpack_kernel(const float* __restrict__ w1,
                             _Float16* __restrict__ w_h,
                             uint32_t* __restrict__ idx_tab) {
    int id = blockIdx.x * 256 + threadIdx.x;
    if (id >= NGROUP * 8 * 64) return;
    int e    = id & 7;
    int lane = (id >> 3) & 63;
    int st   = id >> 9;          // 0..279
    int s    = st >> 2;
    int t    = st & 3;           // n-tile
    int g    = lane >> 4;        // k-group
    int c    = lane & 15;        // column within n-tile
    int n    = t * 16 + c;
    int gid  = s * 4 + g;

    int i, j0;
    gid_to_ij(gid, i, j0);
    int j = j0 + e;
    float w = 0.0f;
    if (j > i) {
        int p = i * DIM - (i * (i + 1)) / 2 + (j - i - 1);
        w = w1[p * DIM + n];
    }
    w_h[id] = (_Float16)w;
    if (e == 0 && c == 0 && t == 0) idx_tab[gid] = (uint32_t)i | ((uint32_t)j0 << 8);
}

__global__ __launch_bounds__(256, 2)
void prodres_kernel(const float* __restrict__ x,
                    const _Float16* __restrict__ w_h,
                    const uint32_t* __restrict__ idx_tab,
                    float* __restrict__ out) {
    __shared__ _Float16 xs[BM * XS_STRIDE];   // 36.9 KB
    __shared__ uint32_t idx_s[NGROUP];

    const int t    = threadIdx.x;
    const int lane = t & 63;
    const int wave = t >> 6;
    const long brow = (long)blockIdx.x * BM;

    // stage x tile [BM][64] -> xs as fp16, coalesced float4 loads
    #pragma unroll
    for (int it = 0; it < 16; ++it) {
        int row = it * 16 + (t >> 4);
        int c   = (t & 15) * 4;
        float4 v = *reinterpret_cast<const float4*>(x + (brow + row) * DIM + c);
        half4_t h;
        h[0] = (_Float16)v.x; h[1] = (_Float16)v.y;
        h[2] = (_Float16)v.z; h[3] = (_Float16)v.w;
        *reinterpret_cast<half4_t*>(&xs[row * XS_STRIDE + c]) = h;
    }
    for (int ii = t; ii < NGROUP; ii += 256) idx_s[ii] = idx_tab[ii];
    __syncthreads();

    const int lrow = lane & 15;   // A row / C col within 16-tile
    const int g    = lane >> 4;   // k-group (owns k = g*8 + e)

    // per-m LDS row base pointers (wave owns rows wave*64 .. wave*64+63)
    const _Float16* xr[4];
    #pragma unroll
    for (int m = 0; m < 4; ++m)
        xr[m] = &xs[(wave * 64 + m * 16 + lrow) * XS_STRIDE];

    f32x4 acc[4][4];
    #pragma unroll
    for (int m = 0; m < 4; ++m)
        #pragma unroll
        for (int n = 0; n < 4; ++n) {
            f32x4 z = {0.f, 0.f, 0.f, 0.f};
            acc[m][n] = z;
        }

    const half8_t* wp = reinterpret_cast<const half8_t*>(w_h);

    // ---- prologue: load step-0 B-frags (global) and A-sources (LDS) ----
    half8_t bcur[4];
    #pragma unroll
    for (int n = 0; n < 4; ++n) bcur[n] = wp[n * 64 + lane];

    uint32_t ij0 = idx_s[g];
    int i_c  = (int)(ij0 & 0xffu);
    int j0_c = (int)((ij0 >> 8) & 0xffu);
    _Float16 xi_c[4];
    half8_t  xj_c[4];
    #pragma unroll
    for (int m = 0; m < 4; ++m) {
        xi_c[m] = xr[m][i_c];
        xj_c[m] = *reinterpret_cast<const half8_t*>(xr[m] + j0_c);
    }

    #pragma unroll 2
    for (int s = 0; s < NSTEP; ++s) {
        int sn = (s + 1 < NSTEP) ? s + 1 : s;   // clamped prefetch index

        // ---- prefetch next B-frags (global, L1/L2-hot) ----
        half8_t bnxt[4];
        #pragma unroll
        for (int n = 0; n < 4; ++n)
            bnxt[n] = wp[(sn * 4 + n) * 64 + lane];

        // ---- prefetch next A-sources (LDS) ----
        uint32_t ijn = idx_s[sn * 4 + g];
        int i_n  = (int)(ijn & 0xffu);
        int j0_n = (int)((ijn >> 8) & 0xffu);
        _Float16 xi_n[4];
        half8_t  xj_n[4];
        #pragma unroll
        for (int m = 0; m < 4; ++m) {
            xi_n[m] = xr[m][i_n];
            xj_n[m] = *reinterpret_cast<const half8_t*>(xr[m] + j0_n);
        }

        // ---- compute A-frags for current step (VALU only) ----
        half8_t ah[4];
        #pragma unroll
        for (int m = 0; m < 4; ++m) {
            half2_t xi2 = {xi_c[m], xi_c[m]};
            half2_t* ap = reinterpret_cast<half2_t*>(&ah[m]);
            const half2_t* jp = reinterpret_cast<const half2_t*>(&xj_c[m]);
            #pragma unroll
            for (int e2 = 0; e2 < 4; ++e2) ap[e2] = xi2 * jp[e2];
        }

        // ---- 16 MFMAs ----
        #pragma unroll
        for (int m = 0; m < 4; ++m)
            #pragma unroll
            for (int n = 0; n < 4; ++n)
                acc[m][n] = __builtin_amdgcn_mfma_f32_16x16x32_f16(ah[m], bcur[n], acc[m][n], 0, 0, 0);

        // ---- rotate pipeline registers ----
        #pragma unroll
        for (int n = 0; n < 4; ++n) bcur[n] = bnxt[n];
        #pragma unroll
        for (int m = 0; m < 4; ++m) { xi_c[m] = xi_n[m]; xj_c[m] = xj_n[m]; }
    }

    // ---- epilogue: C/D layout col=lane&15, row=(lane>>4)*4+reg ----
    // residual from fp16 LDS copy (err <= 2.7e-3, inside 0.0625 budget)
    #pragma unroll
    for (int m = 0; m < 4; ++m)
        #pragma unroll
        for (int q = 0; q < 4; ++q) {
            int lr = wave * 64 + m * 16 + g * 4 + q;
            long row = brow + lr;
            #pragma unroll
            for (int n = 0; n < 4; ++n) {
                int col = n * 16 + lrow;
                out[row * DIM + col] = acc[m][n][q] + (float)xs[lr * XS_STRIDE + col];
            }
        }
}

extern "C" void kernel_launch(void* const* d_in, const int* in_sizes, int n_in,
                              void* d_out, int out_size, void* d_ws, size_t ws_size,
                              hipStream_t stream) {
    const float* x  = (const float*)d_in[0];
    const float* w1 = (const float*)d_in[1];
    float* out = (float*)d_out;

    const size_t WELEMS = (size_t)NGROUP * 8 * 64;  // 143360 fp16 elems
    _Float16* w_h = (_Float16*)d_ws;
    uint32_t* idx_tab = (uint32_t*)(w_h + WELEMS);

    int b_total = in_sizes[0] / DIM;   // 131072

    wpack_kernel<<<(NGROUP * 8 * 64 + 255) / 256, 256, 0, stream>>>(w1, w_h, idx_tab);
    prodres_kernel<<<b_total / BM, 256, 0, stream>>>(x, w_h, idx_tab, out);
}